// Round 10
// baseline (585.575 us; speedup 1.0000x reference)
//
#include <hip/hip_runtime.h>

// VectorQuantizer: z (32,64,64,64) fp32, embedding_w (2048,64) fp32.
// Outputs concat: quantized_out (32,64,64,64) | indices (32,64,64) as float | loss (1)
//
// R14 = R11 (verified pass, absmax 0; vq_main 129us) with register-state cuts.
// R13 lesson: rocprof VGPR_Count=52 excludes the acc side of the unified
// file; true per-wave state ~130-150 regs -> 3 waves/SIMD -> the measured
// 39.8% occupancy. launch_bounds changes provoke compiler spills (R12/R13);
// instead shrink the state:
//   (a) 32-row blocks (grid 4096, mt in {0,1}): afrag 32->16 VGPRs,
//       rmin 16->8, thrr 16->8, LDS 15.4KB->7.5KB. Same total work.
//   (b) fold the distance into the MFMA: zsh stores bf16(-2*z) (exact x-2),
//       acc initialized to {bv,bv,bv,bv} (C/D col=lane&15=code) -> v=acc
//       directly; removes 16 v_fma + 16 zero-inits per sweep iteration.
//       Same error structure as the verified margin analysis (identical
//       bf16 conversions, fp32 accumulation; 4x/20x slack holds).
// Unchanged: (256,4), vq_bsum 8x256, fragment-order codebook, two barrier-
// free sweeps, margin formula, exact fp32 rescore chain, packed-key
// (d<<32|k) atomicMin first-index tie-break, STE epilogue, double loss.

#define KCODES   2048
#define CDIM     64
#define OUT_Q    0
#define OUT_IDX  8388608
#define OUT_LOSS 8519680
#define ZSTR     72          // ushort stride per LDS z row
#define BR       32          // rows per block
#define CAP      32
#define B_MAX    1.6e-5f     // > 64*(1/2048)^2

typedef float f2    __attribute__((ext_vector_type(2)));
typedef float f32x4 __attribute__((ext_vector_type(4)));
typedef short s16x8 __attribute__((ext_vector_type(8)));   // 8 bf16 (4 VGPRs)
typedef unsigned long long u64;
typedef unsigned short u16;
typedef unsigned int u32;

// f32 -> bf16 bits, RTNE
__device__ __forceinline__ u16 f2bf(float x) {
    u32 u = __float_as_uint(x);
    return (u16)((u + 0x7fffu + ((u >> 16) & 1u)) >> 16);
}
// order-preserving float -> u32 (works for negatives); uint-min == float-min
__device__ __forceinline__ u32 encf(float f) {
    u32 b = __float_as_uint(f);
    return (b & 0x80000000u) ? ~b : (b | 0x80000000u);
}
__device__ __forceinline__ float decf(u32 e) {
    return __uint_as_float((e & 0x80000000u) ? (e ^ 0x80000000u) : ~e);
}

__device__ __forceinline__ float fc(const float4& v, int i) {
    return i == 0 ? v.x : (i == 1 ? v.y : (i == 2 ? v.z : v.w));
}

__device__ __forceinline__ float pairwise64(const float a[64]) {
    float r[8];
#pragma unroll
    for (int j = 0; j < 8; ++j) r[j] = a[j];
#pragma unroll
    for (int m = 1; m < 8; ++m)
#pragma unroll
        for (int j = 0; j < 8; ++j) r[j] = __fadd_rn(r[j], a[m * 8 + j]);
    float s01 = __fadd_rn(r[0], r[1]);
    float s23 = __fadd_rn(r[2], r[3]);
    float s45 = __fadd_rn(r[4], r[5]);
    float s67 = __fadd_rn(r[6], r[7]);
    return __fadd_rn(__fadd_rn(s01, s23), __fadd_rn(s45, s67));
}

// exact reference distance (bit-exact chain, verified R1-R13)
__device__ __forceinline__ float exact_d(const float* __restrict__ zp,
                                         const float* __restrict__ wk,
                                         float Sr, float bk) {
    float acc = 0.f;
#pragma unroll
    for (int c0 = 0; c0 < 64; c0 += 4) {
        const float4 wc = *(const float4*)(wk + c0);
        acc = __builtin_fmaf(zp[(size_t)(c0 + 0) * 4096], wc.x, acc);
        acc = __builtin_fmaf(zp[(size_t)(c0 + 1) * 4096], wc.y, acc);
        acc = __builtin_fmaf(zp[(size_t)(c0 + 2) * 4096], wc.z, acc);
        acc = __builtin_fmaf(zp[(size_t)(c0 + 3) * 4096], wc.w, acc);
    }
    float Sb = __fadd_rn(Sr, bk);
    return __builtin_fmaf(acc, -2.0f, Sb);
}

// ------- kernel A: b_k, plus codebook -> bf16 in MFMA fragment order -------
__global__ __launch_bounds__(256) void vq_bsum(const float* __restrict__ w,
                                               float* __restrict__ bsum,
                                               u16* __restrict__ wf0,
                                               u16* __restrict__ wf1) {
    int k = blockIdx.x * 256 + threadIdx.x;
    const float4* wr = (const float4*)(w + (size_t)k * CDIM);
    float4 v[16];
    float a[64];
#pragma unroll
    for (int m = 0; m < 16; ++m) {
        v[m] = wr[m];
        a[4 * m + 0] = __fmul_rn(v[m].x, v[m].x);
        a[4 * m + 1] = __fmul_rn(v[m].y, v[m].y);
        a[4 * m + 2] = __fmul_rn(v[m].z, v[m].z);
        a[4 * m + 3] = __fmul_rn(v[m].w, v[m].w);
    }
    bsum[k] = pairwise64(a);

    // fragment order: lane l of group g=k>>4 wants code g*16+(l&15),
    // dims (l>>4)*8..+8 (half0) / 32+(l>>4)*8..+8 (half1)
    const int g = k >> 4, i16 = k & 15;
#pragma unroll
    for (int h = 0; h < 2; ++h) {
        u16* wf = h ? wf1 : wf0;
#pragma unroll
        for (int o = 0; o < 4; ++o) {
            float4 va = v[h * 8 + o * 2];
            float4 vb = v[h * 8 + o * 2 + 1];
            u64 p0 = (u64)f2bf(va.x) | ((u64)f2bf(va.y) << 16)
                   | ((u64)f2bf(va.z) << 32) | ((u64)f2bf(va.w) << 48);
            u64 p1 = (u64)f2bf(vb.x) | ((u64)f2bf(vb.y) << 16)
                   | ((u64)f2bf(vb.z) << 32) | ((u64)f2bf(vb.w) << 48);
            u64* dst = (u64*)(wf + (size_t)(g * 64 + o * 16 + i16) * 8);
            dst[0] = p0; dst[1] = p1;
        }
    }
}

// ------------------- kernel B: main VQ (barrier-free sweeps) -------------------
__global__ __launch_bounds__(256, 4) void vq_main(const float* __restrict__ z,
                                                  const float* __restrict__ w,
                                                  const float* __restrict__ bsum,
                                                  const u16* __restrict__ wf0,
                                                  const u16* __restrict__ wf1,
                                                  float* __restrict__ out,
                                                  double* __restrict__ partial) {
    __shared__ u16 zsh[BR * ZSTR];                 // 4608 B bf16(-2z) tile
    __shared__ float Ssh[BR];
    __shared__ u32 rowmin[BR];                     // encoded float min
    __shared__ float thr[BR];
    __shared__ u64 skey[BR];
    __shared__ u32 cnt[BR];
    __shared__ u16 cand[BR][CAP];                  // 2048 B
    __shared__ double lredd[4];

    const int t  = threadIdx.x;
    const int l  = t & 63;
    const int wv = t >> 6;                          // wave 0..3 = code slice
    const int bb = blockIdx.x;                      // 4096 blocks, 32 rows each
    const size_t zbase = (size_t)(bb >> 7) * 262144 + (size_t)(bb & 127) * 32;

    if (t < BR) {
        skey[t]   = 0xFFFFFFFFFFFFFFFFull;
        cnt[t]    = 0u;
        rowmin[t] = 0xFFFFFFFFu;
    }

    // ---- stage z tile as bf16(-2z) (coalesced f2 reads; x-2 exact) ----
#pragma unroll
    for (int m = 0; m < 4; ++m) {
        int i = m * 256 + t;                        // 0..1023 f2 elements
        int p = i & 15;                             // row pair 0..15
        int c = i >> 4;                             // dim 0..63
        f2 v = *(const f2*)(z + zbase + (size_t)c * 4096 + 2 * p);
        zsh[(2 * p)     * ZSTR + c] = f2bf(-2.0f * v.x);
        zsh[(2 * p + 1) * ZSTR + c] = f2bf(-2.0f * v.y);
    }

    // ---- exact S per row (verified streaming pairwise) ----
    if (t < BR) {
        const float* zp = z + zbase + t;
        float r[8];
#pragma unroll
        for (int j = 0; j < 8; ++j) {
            float v = zp[(size_t)j * 4096];
            r[j] = __fmul_rn(v, v);
        }
#pragma unroll
        for (int m = 1; m < 8; ++m)
#pragma unroll
            for (int j = 0; j < 8; ++j) {
                float v = zp[(size_t)(m * 8 + j) * 4096];
                r[j] = __fadd_rn(r[j], __fmul_rn(v, v));
            }
        float s01 = __fadd_rn(r[0], r[1]);
        float s23 = __fadd_rn(r[2], r[3]);
        float s45 = __fadd_rn(r[4], r[5]);
        float s67 = __fadd_rn(r[6], r[7]);
        Ssh[t] = __fadd_rn(__fadd_rn(s01, s23), __fadd_rn(s45, s67));
    }
    __syncthreads();

    // ---- 2 resident A-tiles: afrag[mt] covers rows mt*16..+16 ----
    s16x8 afrag[2][2];
#pragma unroll
    for (int mt = 0; mt < 2; ++mt)
#pragma unroll
        for (int kb = 0; kb < 2; ++kb)
            afrag[mt][kb] = *(const s16x8*)&zsh[(mt * 16 + (l & 15)) * ZSTR
                                               + kb * 32 + (l >> 4) * 8];

    const int gbase = __builtin_amdgcn_readfirstlane(wv) * 32;  // 32 groups = 512 codes

    // ====== sweep 1: per-row min of v = b - 2C (acc init = b; no barriers) ==
    float rmin[2][4];
#pragma unroll
    for (int mt = 0; mt < 2; ++mt)
#pragma unroll
        for (int rg = 0; rg < 4; ++rg) rmin[mt][rg] = __builtin_inff();

    {
        s16x8 nb0 = *(const s16x8*)(wf0 + (size_t)(gbase * 64 + l) * 8);
        s16x8 nb1 = *(const s16x8*)(wf1 + (size_t)(gbase * 64 + l) * 8);
        float nbv = bsum[gbase * 16 + (l & 15)];
        for (int g2 = 0; g2 < 32; ++g2) {
            s16x8 b0 = nb0, b1 = nb1;
            float bv = nbv;
            if (g2 < 31) {
                int gn = gbase + g2 + 1;
                nb0 = *(const s16x8*)(wf0 + (size_t)(gn * 64 + l) * 8);
                nb1 = *(const s16x8*)(wf1 + (size_t)(gn * 64 + l) * 8);
                nbv = bsum[gn * 16 + (l & 15)];
            }
#pragma unroll
            for (int mt = 0; mt < 2; ++mt) {
                f32x4 acc = {bv, bv, bv, bv};      // init = b_code (col=lane&15)
                acc = __builtin_amdgcn_mfma_f32_16x16x32_bf16(afrag[mt][0], b0, acc, 0, 0, 0);
                acc = __builtin_amdgcn_mfma_f32_16x16x32_bf16(afrag[mt][1], b1, acc, 0, 0, 0);
#pragma unroll
                for (int rg = 0; rg < 4; ++rg)
                    rmin[mt][rg] = fminf(rmin[mt][rg], acc[rg]);
            }
        }
    }

    // ---- cross-lane (over l&15) + cross-wave row-min merge ----
#pragma unroll
    for (int mt = 0; mt < 2; ++mt)
#pragma unroll
        for (int rg = 0; rg < 4; ++rg) {
            float m = rmin[mt][rg];
            m = fminf(m, __shfl_xor(m, 1, 64));
            m = fminf(m, __shfl_xor(m, 2, 64));
            m = fminf(m, __shfl_xor(m, 4, 64));
            m = fminf(m, __shfl_xor(m, 8, 64));
            if ((l & 15) == 0)
                atomicMin(&rowmin[mt * 16 + (l >> 4) * 4 + rg], encf(m));
        }
    __syncthreads();

    if (t < BR) {
        float S = Ssh[t];
        thr[t] = decf(rowmin[t])
               + (0.03125f * sqrtf(S * B_MAX) + 7.6294e-6f * (S + 1.0f));
    }
    __syncthreads();

    // ================= sweep 2: collect candidates (no barriers) ===========
    float thrr[2][4];
#pragma unroll
    for (int mt = 0; mt < 2; ++mt)
#pragma unroll
        for (int rg = 0; rg < 4; ++rg)
            thrr[mt][rg] = thr[mt * 16 + (l >> 4) * 4 + rg];

    {
        s16x8 nb0 = *(const s16x8*)(wf0 + (size_t)(gbase * 64 + l) * 8);
        s16x8 nb1 = *(const s16x8*)(wf1 + (size_t)(gbase * 64 + l) * 8);
        float nbv = bsum[gbase * 16 + (l & 15)];
        for (int g2 = 0; g2 < 32; ++g2) {
            const int g = gbase + g2;
            s16x8 b0 = nb0, b1 = nb1;
            float bv = nbv;
            if (g2 < 31) {
                int gn = g + 1;
                nb0 = *(const s16x8*)(wf0 + (size_t)(gn * 64 + l) * 8);
                nb1 = *(const s16x8*)(wf1 + (size_t)(gn * 64 + l) * 8);
                nbv = bsum[gn * 16 + (l & 15)];
            }
#pragma unroll
            for (int mt = 0; mt < 2; ++mt) {
                f32x4 acc = {bv, bv, bv, bv};
                acc = __builtin_amdgcn_mfma_f32_16x16x32_bf16(afrag[mt][0], b0, acc, 0, 0, 0);
                acc = __builtin_amdgcn_mfma_f32_16x16x32_bf16(afrag[mt][1], b1, acc, 0, 0, 0);
#pragma unroll
                for (int rg = 0; rg < 4; ++rg) {
                    if (acc[rg] <= thrr[mt][rg]) {
                        int row = mt * 16 + (l >> 4) * 4 + rg;
                        u32 pos = atomicAdd(&cnt[row], 1u);
                        if (pos < CAP)
                            cand[row][pos] = (u16)(g * 16 + (l & 15));
                    }
                }
            }
        }
    }
    __syncthreads();

    // ================= exact rescore (bit-exact fp32 chain) =================
    {
        const int row  = t & (BR - 1);
        const int part = t >> 5;                   // 8 threads per row
        const float* zp = z + zbase + row;
        const float Sr = Ssh[row];
        u32 n = cnt[row];
        if (n <= CAP) {
            for (u32 i = part; i < n; i += 8) {
                int k = cand[row][i];
                float d = exact_d(zp, w + (size_t)k * CDIM, Sr, bsum[k]);
                atomicMin(&skey[row], ((u64)__float_as_uint(d) << 32) | (u64)(u32)k);
            }
        } else {                                   // overflow: exact full scan
            for (int k = part; k < KCODES; k += 8) {
                float d = exact_d(zp, w + (size_t)k * CDIM, Sr, bsum[k]);
                atomicMin(&skey[row], ((u64)__float_as_uint(d) << 32) | (u64)(u32)k);
            }
        }
    }
    __syncthreads();

    // ===== epilogue: thread t owns row t&31, dims [(t>>5)*8, +8) =====
    {
        const int row   = t & (BR - 1);
        const int chunk = t >> 5;                  // 0..7
        const u32 kq = (u32)(skey[row] & 0xFFFFFFFFull);
        if (chunk == 0) out[OUT_IDX + (size_t)bb * BR + row] = (float)kq;

        const float* wq = w + (size_t)kq * CDIM + chunk * 8;
        const float* zp = z + zbase + row;
        double lacc = 0.0;
#pragma unroll
        for (int c4 = 0; c4 < 8; c4 += 4) {
            const float4 q4 = *(const float4*)(wq + c4);
#pragma unroll
            for (int i = 0; i < 4; ++i) {
                int c = chunk * 8 + c4 + i;
                float zv = zp[(size_t)c * 4096];
                float d1  = __fsub_rn(fc(q4, i), zv);  // quantized - zp
                float val = __fadd_rn(zv, d1);         // zp + (q - zp)
                out[OUT_Q + zbase + (size_t)c * 4096 + row] = val;
                lacc += (double)__fmul_rn(d1, d1);
            }
        }
#pragma unroll
        for (int off = 1; off < 64; off <<= 1) lacc += __shfl_xor(lacc, off, 64);
        if (l == 0) lredd[wv] = lacc;
    }
    __syncthreads();
    if (t == 0) partial[bb] = lredd[0] + lredd[1] + lredd[2] + lredd[3];
}

// ---------------- kernel C: reduce loss partials (4096 doubles) ----------------
__global__ __launch_bounds__(256) void vq_loss(const double* __restrict__ partial,
                                               float* __restrict__ out) {
    int t = threadIdx.x;
    double s = 0.0;
#pragma unroll
    for (int i = 0; i < 16; ++i) s += partial[t + i * 256];
#pragma unroll
    for (int off = 1; off < 64; off <<= 1) s += __shfl_xor(s, off, 64);
    __shared__ double sr[4];
    if ((t & 63) == 0) sr[t >> 6] = s;
    __syncthreads();
    if (t == 0)
        out[OUT_LOSS] = (float)((sr[0] + sr[1] + sr[2] + sr[3]) * (0.25 / 8388608.0));
}

extern "C" void kernel_launch(void* const* d_in, const int* in_sizes, int n_in,
                              void* d_out, int out_size, void* d_ws, size_t ws_size,
                              hipStream_t stream) {
    (void)in_sizes; (void)n_in; (void)out_size; (void)ws_size;
    const float* z = (const float*)d_in[0];
    const float* w = (const float*)d_in[1];
    float* out     = (float*)d_out;

    float*  bsum    = (float*)d_ws;                            // 8 KB
    u16*    wf0     = (u16*)((char*)d_ws + 8192);              // 128 KB
    u16*    wf1     = (u16*)((char*)d_ws + 8192 + 131072);     // 128 KB
    double* partial = (double*)((char*)d_ws + 8192 + 262144);  // 32 KB

    vq_bsum<<<8, 256, 0, stream>>>(w, bsum, wf0, wf1);
    vq_main<<<4096, 256, 0, stream>>>(z, w, bsum, wf0, wf1, out, partial);
    vq_loss<<<1, 256, 0, stream>>>(partial, out);
}

// Round 11
// 201.969 us; speedup vs baseline: 2.8993x; 2.8993x over previous
//
#include <hip/hip_runtime.h>

// VectorQuantizer: z (32,64,64,64) fp32, embedding_w (2048,64) fp32.
// Outputs concat: quantized_out (32,64,64,64) | indices (32,64,64) as float | loss (1)
//
// R15 = R11 (proven: vq_main 129us, FETCH 29.7MB no-spill, absmax 0) plus
// EXACTLY ONE lever: the acc-init fold that R14 field-verified for numerics
// (R14 passed absmax 0; its slowness was allocator spill from the BR=32
// restructure, NOT the fold):
//   - zsh stores bf16(-2*z) (x-2 exact: exponent+1, same bf16 rel-error)
//   - MFMA accumulator initialized to {bv,bv,bv,bv} (C/D col=lane&15=code)
//   - v = acc[rg] directly -> deletes 16 v_fmaf + keeps 4 movs per iter
//     in BOTH sweeps (~20-25% of sweep VALU).
// R12/R13/R14 lesson: this compiler spills perversely under restructures /
// launch-bound changes; everything else is byte-identical to R11, including
// (256,4), 64-row blocks, grid 2048, CAP 32, vq_bsum 8x256.
//
// R11 recap: barrier-free MFMA prune + exact rescore.
//   - vq_bsum pre-swizzles the bf16 codebook into MFMA fragment order
//     (wf0/wf1[g*64+lane] = the exact 16B lane fragment) -> sweep B-operands
//     are direct per-lane global dwordx4 loads from L2 (256KB resident).
//   - codes split across waves (wave wv owns codes [wv*512,+512), all 64
//     rows as 4 resident A-tiles) -> disjoint B traffic, independent waves.
//   - margin = 2^-5*sqrt(S*B_MAX) + 2^-17*(S+1) provably contains the
//     reference argmin (bf16-conv error 2^-8*sqrt(S*b) + fp32 chain rounding,
//     2-7x slack; b_k <= 64/2048^2 analytically; bv tiny vs margin).
//   - exact fp32 rescore chain (bit-exact, verified R1-R14), packed-key
//     (d<<32|k) atomicMin first-index tie-break, STE epilogue, double loss.

#define KCODES   2048
#define CDIM     64
#define OUT_Q    0
#define OUT_IDX  8388608
#define OUT_LOSS 8519680
#define ZSTR     72          // ushort stride per LDS z row
#define CAP      32
#define B_MAX    1.6e-5f     // > 64*(1/2048)^2

typedef float f2    __attribute__((ext_vector_type(2)));
typedef float f32x4 __attribute__((ext_vector_type(4)));
typedef short s16x8 __attribute__((ext_vector_type(8)));   // 8 bf16 (4 VGPRs)
typedef unsigned long long u64;
typedef unsigned short u16;
typedef unsigned int u32;

// f32 -> bf16 bits, RTNE
__device__ __forceinline__ u16 f2bf(float x) {
    u32 u = __float_as_uint(x);
    return (u16)((u + 0x7fffu + ((u >> 16) & 1u)) >> 16);
}
// order-preserving float -> u32 (works for negatives); uint-min == float-min
__device__ __forceinline__ u32 encf(float f) {
    u32 b = __float_as_uint(f);
    return (b & 0x80000000u) ? ~b : (b | 0x80000000u);
}
__device__ __forceinline__ float decf(u32 e) {
    return __uint_as_float((e & 0x80000000u) ? (e ^ 0x80000000u) : ~e);
}

__device__ __forceinline__ float fc(const float4& v, int i) {
    return i == 0 ? v.x : (i == 1 ? v.y : (i == 2 ? v.z : v.w));
}

__device__ __forceinline__ float pairwise64(const float a[64]) {
    float r[8];
#pragma unroll
    for (int j = 0; j < 8; ++j) r[j] = a[j];
#pragma unroll
    for (int m = 1; m < 8; ++m)
#pragma unroll
        for (int j = 0; j < 8; ++j) r[j] = __fadd_rn(r[j], a[m * 8 + j]);
    float s01 = __fadd_rn(r[0], r[1]);
    float s23 = __fadd_rn(r[2], r[3]);
    float s45 = __fadd_rn(r[4], r[5]);
    float s67 = __fadd_rn(r[6], r[7]);
    return __fadd_rn(__fadd_rn(s01, s23), __fadd_rn(s45, s67));
}

// exact reference distance (bit-exact chain, verified R1-R14)
__device__ __forceinline__ float exact_d(const float* __restrict__ zp,
                                         const float* __restrict__ wk,
                                         float Sr, float bk) {
    float acc = 0.f;
#pragma unroll
    for (int c0 = 0; c0 < 64; c0 += 4) {
        const float4 wc = *(const float4*)(wk + c0);
        acc = __builtin_fmaf(zp[(size_t)(c0 + 0) * 4096], wc.x, acc);
        acc = __builtin_fmaf(zp[(size_t)(c0 + 1) * 4096], wc.y, acc);
        acc = __builtin_fmaf(zp[(size_t)(c0 + 2) * 4096], wc.z, acc);
        acc = __builtin_fmaf(zp[(size_t)(c0 + 3) * 4096], wc.w, acc);
    }
    float Sb = __fadd_rn(Sr, bk);
    return __builtin_fmaf(acc, -2.0f, Sb);
}

// ------- kernel A: b_k, plus codebook -> bf16 in MFMA fragment order -------
__global__ __launch_bounds__(256) void vq_bsum(const float* __restrict__ w,
                                               float* __restrict__ bsum,
                                               u16* __restrict__ wf0,
                                               u16* __restrict__ wf1) {
    int k = blockIdx.x * 256 + threadIdx.x;
    const float4* wr = (const float4*)(w + (size_t)k * CDIM);
    float4 v[16];
    float a[64];
#pragma unroll
    for (int m = 0; m < 16; ++m) {
        v[m] = wr[m];
        a[4 * m + 0] = __fmul_rn(v[m].x, v[m].x);
        a[4 * m + 1] = __fmul_rn(v[m].y, v[m].y);
        a[4 * m + 2] = __fmul_rn(v[m].z, v[m].z);
        a[4 * m + 3] = __fmul_rn(v[m].w, v[m].w);
    }
    bsum[k] = pairwise64(a);

    // fragment order: lane l of group g=k>>4 wants code g*16+(l&15),
    // dims (l>>4)*8..+8 (half0) / 32+(l>>4)*8..+8 (half1)
    const int g = k >> 4, i16 = k & 15;
#pragma unroll
    for (int h = 0; h < 2; ++h) {
        u16* wf = h ? wf1 : wf0;
#pragma unroll
        for (int o = 0; o < 4; ++o) {
            float4 va = v[h * 8 + o * 2];
            float4 vb = v[h * 8 + o * 2 + 1];
            u64 p0 = (u64)f2bf(va.x) | ((u64)f2bf(va.y) << 16)
                   | ((u64)f2bf(va.z) << 32) | ((u64)f2bf(va.w) << 48);
            u64 p1 = (u64)f2bf(vb.x) | ((u64)f2bf(vb.y) << 16)
                   | ((u64)f2bf(vb.z) << 32) | ((u64)f2bf(vb.w) << 48);
            u64* dst = (u64*)(wf + (size_t)(g * 64 + o * 16 + i16) * 8);
            dst[0] = p0; dst[1] = p1;
        }
    }
}

// ------------------- kernel B: main VQ (barrier-free sweeps) -------------------
__global__ __launch_bounds__(256, 4) void vq_main(const float* __restrict__ z,
                                                  const float* __restrict__ w,
                                                  const float* __restrict__ bsum,
                                                  const u16* __restrict__ wf0,
                                                  const u16* __restrict__ wf1,
                                                  float* __restrict__ out,
                                                  double* __restrict__ partial) {
    __shared__ u16 zsh[64 * ZSTR];                 // 9216 B bf16(-2z) tile
    __shared__ float Ssh[64];
    __shared__ u32 rowmin[64];                     // encoded float min
    __shared__ float thr[64];
    __shared__ u64 skey[64];
    __shared__ u32 cnt[64];
    __shared__ u16 cand[64][CAP];
    __shared__ double lredd[4];

    const int t  = threadIdx.x;
    const int l  = t & 63;
    const int wv = t >> 6;                          // wave 0..3 = code slice
    const int bb = blockIdx.x;                      // 2048 blocks, 64 rows each
    const size_t zbase = (size_t)(bb >> 6) * 262144 + (size_t)(bb & 63) * 64;

    if (t < 64) {
        skey[t]   = 0xFFFFFFFFFFFFFFFFull;
        cnt[t]    = 0u;
        rowmin[t] = 0xFFFFFFFFu;
    }

    // ---- stage z tile as bf16(-2z) (coalesced f2 reads; x-2 exact) ----
#pragma unroll
    for (int m = 0; m < 8; ++m) {
        int i = m * 256 + t;                        // 0..2047 f2 elements
        int p = i & 31;                             // row pair
        int c = i >> 5;                             // dim
        f2 v = *(const f2*)(z + zbase + (size_t)c * 4096 + 2 * p);
        zsh[(2 * p)     * ZSTR + c] = f2bf(-2.0f * v.x);
        zsh[(2 * p + 1) * ZSTR + c] = f2bf(-2.0f * v.y);
    }

    // ---- exact S per row (verified streaming pairwise) ----
    if (t < 64) {
        const float* zp = z + zbase + t;
        float r[8];
#pragma unroll
        for (int j = 0; j < 8; ++j) {
            float v = zp[(size_t)j * 4096];
            r[j] = __fmul_rn(v, v);
        }
#pragma unroll
        for (int m = 1; m < 8; ++m)
#pragma unroll
            for (int j = 0; j < 8; ++j) {
                float v = zp[(size_t)(m * 8 + j) * 4096];
                r[j] = __fadd_rn(r[j], __fmul_rn(v, v));
            }
        float s01 = __fadd_rn(r[0], r[1]);
        float s23 = __fadd_rn(r[2], r[3]);
        float s45 = __fadd_rn(r[4], r[5]);
        float s67 = __fadd_rn(r[6], r[7]);
        Ssh[t] = __fadd_rn(__fadd_rn(s01, s23), __fadd_rn(s45, s67));
    }
    __syncthreads();

    // ---- 4 resident A-tiles: afrag[mt] covers rows mt*16..+16 ----
    s16x8 afrag[4][2];
#pragma unroll
    for (int mt = 0; mt < 4; ++mt)
#pragma unroll
        for (int kb = 0; kb < 2; ++kb)
            afrag[mt][kb] = *(const s16x8*)&zsh[(mt * 16 + (l & 15)) * ZSTR
                                               + kb * 32 + (l >> 4) * 8];

    const int gbase = __builtin_amdgcn_readfirstlane(wv) * 32;  // 32 groups = 512 codes

    // ==== sweep 1: per-row min of v = b - 2C (acc init = b; no barriers) ====
    float rmin[4][4];
#pragma unroll
    for (int mt = 0; mt < 4; ++mt)
#pragma unroll
        for (int rg = 0; rg < 4; ++rg) rmin[mt][rg] = __builtin_inff();

    {
        s16x8 nb0 = *(const s16x8*)(wf0 + (size_t)(gbase * 64 + l) * 8);
        s16x8 nb1 = *(const s16x8*)(wf1 + (size_t)(gbase * 64 + l) * 8);
        float nbv = bsum[gbase * 16 + (l & 15)];
        for (int g2 = 0; g2 < 32; ++g2) {
            s16x8 b0 = nb0, b1 = nb1;
            float bv = nbv;
            if (g2 < 31) {
                int gn = gbase + g2 + 1;
                nb0 = *(const s16x8*)(wf0 + (size_t)(gn * 64 + l) * 8);
                nb1 = *(const s16x8*)(wf1 + (size_t)(gn * 64 + l) * 8);
                nbv = bsum[gn * 16 + (l & 15)];
            }
#pragma unroll
            for (int mt = 0; mt < 4; ++mt) {
                f32x4 acc = {bv, bv, bv, bv};      // init = b_code (col=lane&15)
                acc = __builtin_amdgcn_mfma_f32_16x16x32_bf16(afrag[mt][0], b0, acc, 0, 0, 0);
                acc = __builtin_amdgcn_mfma_f32_16x16x32_bf16(afrag[mt][1], b1, acc, 0, 0, 0);
#pragma unroll
                for (int rg = 0; rg < 4; ++rg)
                    rmin[mt][rg] = fminf(rmin[mt][rg], acc[rg]);
            }
        }
    }

    // ---- cross-lane (over l&15) + cross-wave row-min merge ----
#pragma unroll
    for (int mt = 0; mt < 4; ++mt)
#pragma unroll
        for (int rg = 0; rg < 4; ++rg) {
            float m = rmin[mt][rg];
            m = fminf(m, __shfl_xor(m, 1, 64));
            m = fminf(m, __shfl_xor(m, 2, 64));
            m = fminf(m, __shfl_xor(m, 4, 64));
            m = fminf(m, __shfl_xor(m, 8, 64));
            if ((l & 15) == 0)
                atomicMin(&rowmin[mt * 16 + (l >> 4) * 4 + rg], encf(m));
        }
    __syncthreads();

    if (t < 64) {
        float S = Ssh[t];
        thr[t] = decf(rowmin[t])
               + (0.03125f * sqrtf(S * B_MAX) + 7.6294e-6f * (S + 1.0f));
    }
    __syncthreads();

    // ================= sweep 2: collect candidates (no barriers) ===========
    float thrr[4][4];
#pragma unroll
    for (int mt = 0; mt < 4; ++mt)
#pragma unroll
        for (int rg = 0; rg < 4; ++rg)
            thrr[mt][rg] = thr[mt * 16 + (l >> 4) * 4 + rg];

    {
        s16x8 nb0 = *(const s16x8*)(wf0 + (size_t)(gbase * 64 + l) * 8);
        s16x8 nb1 = *(const s16x8*)(wf1 + (size_t)(gbase * 64 + l) * 8);
        float nbv = bsum[gbase * 16 + (l & 15)];
        for (int g2 = 0; g2 < 32; ++g2) {
            const int g = gbase + g2;
            s16x8 b0 = nb0, b1 = nb1;
            float bv = nbv;
            if (g2 < 31) {
                int gn = g + 1;
                nb0 = *(const s16x8*)(wf0 + (size_t)(gn * 64 + l) * 8);
                nb1 = *(const s16x8*)(wf1 + (size_t)(gn * 64 + l) * 8);
                nbv = bsum[gn * 16 + (l & 15)];
            }
#pragma unroll
            for (int mt = 0; mt < 4; ++mt) {
                f32x4 acc = {bv, bv, bv, bv};
                acc = __builtin_amdgcn_mfma_f32_16x16x32_bf16(afrag[mt][0], b0, acc, 0, 0, 0);
                acc = __builtin_amdgcn_mfma_f32_16x16x32_bf16(afrag[mt][1], b1, acc, 0, 0, 0);
#pragma unroll
                for (int rg = 0; rg < 4; ++rg) {
                    if (acc[rg] <= thrr[mt][rg]) {
                        int row = mt * 16 + (l >> 4) * 4 + rg;
                        u32 pos = atomicAdd(&cnt[row], 1u);
                        if (pos < CAP)
                            cand[row][pos] = (u16)(g * 16 + (l & 15));
                    }
                }
            }
        }
    }
    __syncthreads();

    // ================= exact rescore (bit-exact fp32 chain) =================
    {
        const int row  = t & 63;
        const int part = t >> 6;                   // 4 threads per row
        const float* zp = z + zbase + row;
        const float Sr = Ssh[row];
        u32 n = cnt[row];
        if (n <= CAP) {
            for (u32 i = part; i < n; i += 4) {
                int k = cand[row][i];
                float d = exact_d(zp, w + (size_t)k * CDIM, Sr, bsum[k]);
                atomicMin(&skey[row], ((u64)__float_as_uint(d) << 32) | (u64)(u32)k);
            }
        } else {                                   // overflow: exact full scan
            for (int k = part; k < KCODES; k += 4) {
                float d = exact_d(zp, w + (size_t)k * CDIM, Sr, bsum[k]);
                atomicMin(&skey[row], ((u64)__float_as_uint(d) << 32) | (u64)(u32)k);
            }
        }
    }
    __syncthreads();

    // ============ epilogue: wave wv owns dim-quarter wv of row l ============
    {
        const int row = l;
        const u32 kq = (u32)(skey[row] & 0xFFFFFFFFull);
        if (wv == 0) out[OUT_IDX + (size_t)bb * 64 + row] = (float)kq;

        const float* wq = w + (size_t)kq * CDIM + wv * 16;
        const float* zp = z + zbase + row;
        double lacc = 0.0;
#pragma unroll
        for (int c4 = 0; c4 < 16; c4 += 4) {
            const float4 q4 = *(const float4*)(wq + c4);
#pragma unroll
            for (int i = 0; i < 4; ++i) {
                int c = wv * 16 + c4 + i;
                float zv = zp[(size_t)c * 4096];
                float d1  = __fsub_rn(fc(q4, i), zv);  // quantized - zp
                float val = __fadd_rn(zv, d1);         // zp + (q - zp)
                out[OUT_Q + zbase + (size_t)c * 4096 + row] = val;
                lacc += (double)__fmul_rn(d1, d1);
            }
        }
#pragma unroll
        for (int off = 1; off < 64; off <<= 1) lacc += __shfl_xor(lacc, off, 64);
        if (l == 0) lredd[wv] = lacc;
    }
    __syncthreads();
    if (t == 0) partial[bb] = lredd[0] + lredd[1] + lredd[2] + lredd[3];
}

// ---------------- kernel C: reduce loss partials (2048 doubles) ----------------
__global__ __launch_bounds__(256) void vq_loss(const double* __restrict__ partial,
                                               float* __restrict__ out) {
    int t = threadIdx.x;
    double s = 0.0;
#pragma unroll
    for (int i = 0; i < 8; ++i) s += partial[t + i * 256];
#pragma unroll
    for (int off = 1; off < 64; off <<= 1) s += __shfl_xor(s, off, 64);
    __shared__ double sr[4];
    if ((t & 63) == 0) sr[t >> 6] = s;
    __syncthreads();
    if (t == 0)
        out[OUT_LOSS] = (float)((sr[0] + sr[1] + sr[2] + sr[3]) * (0.25 / 8388608.0));
}

extern "C" void kernel_launch(void* const* d_in, const int* in_sizes, int n_in,
                              void* d_out, int out_size, void* d_ws, size_t ws_size,
                              hipStream_t stream) {
    (void)in_sizes; (void)n_in; (void)out_size; (void)ws_size;
    const float* z = (const float*)d_in[0];
    const float* w = (const float*)d_in[1];
    float* out     = (float*)d_out;

    float*  bsum    = (float*)d_ws;                            // 8 KB
    u16*    wf0     = (u16*)((char*)d_ws + 8192);              // 128 KB
    u16*    wf1     = (u16*)((char*)d_ws + 8192 + 131072);     // 128 KB
    double* partial = (double*)((char*)d_ws + 8192 + 262144);  // 16 KB

    vq_bsum<<<8, 256, 0, stream>>>(w, bsum, wf0, wf1);
    vq_main<<<2048, 256, 0, stream>>>(z, w, bsum, wf0, wf1, out, partial);
    vq_loss<<<1, 256, 0, stream>>>(partial, out);
}